// Round 9
// baseline (369.772 us; speedup 1.0000x reference)
//
#include <hip/hip_runtime.h>

// ---------- types ----------
typedef __attribute__((ext_vector_type(8))) short short8;
typedef __attribute__((ext_vector_type(4))) short short4v;
typedef __attribute__((ext_vector_type(4))) float f32x4;

static __device__ __forceinline__ short f2bf(float x) {
    unsigned u = __builtin_bit_cast(unsigned, x);
    unsigned r = (u + 0x7fffu + ((u >> 16) & 1u)) >> 16;
    return (short)r;
}

// async global->LDS, 16B per lane: lds dest = uniform base + lane*16
static __device__ __forceinline__ void gld16(const short* g, short* l) {
    __builtin_amdgcn_global_load_lds((const __attribute__((address_space(1))) void*)g,
                                     (__attribute__((address_space(3))) void*)l, 16, 0, 0);
}

#define QL 512
#define VL 2048
#define DM 1024
#define NH 8
#define DH 128
#define NB 8
#define KQ 1088   // 1024 + 64 (U columns padded)

// ---------- merged prep kernel ----------
// ranges: [0,4) cbias | [4,20) conv | [20,2068) castq | [2068,10260) castv | [10260,26900) buildw
__global__ void prep_k(const float* __restrict__ Q, const float* __restrict__ V,
                       const float* __restrict__ la, const float* __restrict__ cw,
                       const float* __restrict__ cb,
                       const float* __restrict__ Wq, const float* __restrict__ bq,
                       const float* __restrict__ Wv, const float* __restrict__ Wu,
                       const float* __restrict__ bu, const float* __restrict__ bias,
                       const float* __restrict__ fcw,
                       float* __restrict__ cbias, short* __restrict__ Aq,
                       short* __restrict__ comb, short* __restrict__ Vb,
                       short* __restrict__ Bq, short* __restrict__ Bv,
                       short* __restrict__ Bfc) {
    const int blk = blockIdx.x, tid = threadIdx.x;
    if (blk < 4) {
        int i = blk * 256 + tid;
        if (i < DM) cbias[i] = bq[i] + bu[i] + bias[i];
    } else if (blk < 20) {
        int m = (blk - 4) * 256 + tid;
        if (m >= NB * QL) return;
        int b = m >> 9, t = m & 511;
        const float* l = la + b * QL;
        float lm = (t > 0)      ? l[t - 1] : 0.f;
        float l0 = l[t];
        float lp = (t < QL - 1) ? l[t + 1] : 0.f;
        short* row = Aq + (size_t)m * KQ + 1024;
#pragma unroll
        for (int k = 0; k < 10; ++k)
            row[k] = f2bf(cb[k] + lm * cw[k * 3 + 0] + l0 * cw[k * 3 + 1] + lp * cw[k * 3 + 2]);
        for (int k = 10; k < 64; ++k) row[k] = 0;
    } else if (blk < 2068) {
        int id = (blk - 20) * 256 + tid;
        int m = id >> 7, kc = (id & 127) * 8;
        const float* p = Q + (size_t)m * DM + kc;
        float4 f0 = *(const float4*)p;
        float4 f1 = *(const float4*)(p + 4);
        short8 v;
        v[0]=f2bf(f0.x); v[1]=f2bf(f0.y); v[2]=f2bf(f0.z); v[3]=f2bf(f0.w);
        v[4]=f2bf(f1.x); v[5]=f2bf(f1.y); v[6]=f2bf(f1.z); v[7]=f2bf(f1.w);
        *(short8*)(Aq + (size_t)m * KQ + kc) = v;
        *(short8*)(comb + (size_t)m * (2 * DM) + DM + kc) = v;
    } else if (blk < 10260) {
        int id = (blk - 2068) * 256 + tid;
        const float* p = V + (size_t)id * 8;
        float4 f0 = *(const float4*)p;
        float4 f1 = *(const float4*)(p + 4);
        short8 v;
        v[0]=f2bf(f0.x); v[1]=f2bf(f0.y); v[2]=f2bf(f0.z); v[3]=f2bf(f0.w);
        v[4]=f2bf(f1.x); v[5]=f2bf(f1.y); v[6]=f2bf(f1.z); v[7]=f2bf(f1.w);
        *(short8*)(Vb + (size_t)id * 8) = v;
    } else {
        int id = (blk - 10260) * 256 + tid;
        const int nq = DM * KQ;             // 1,114,112
        const int nv = DM * DM;             // 1,048,576
        const int nf = DM * 2 * DM;         // 2,097,152  -> total 16640 blocks
        if (id < nq) {
            int n = id / KQ, k = id % KQ;
            float v = (k < 1024) ? Wq[(size_t)n * 1024 + k]
                                 : ((k < 1034) ? Wu[n * 10 + (k - 1024)] : 0.f);
            Bq[id] = f2bf(v);
        } else if (id < nq + nv) {
            int j = id - nq;
            Bv[j] = f2bf(Wv[j]);
        } else if (id < nq + nv + nf) {
            int j = id - nq - nv;
            Bfc[j] = f2bf(fcw[j]);
        }
    }
}

// ---------- m97-style MFMA GEMM (round-7 4-wave form) ----------
// MODE 0: v_s — bf16 out + transposed out; MODE 1: q_s — bf16 out; MODE 2: fc — f32 tanh
template <int MODE>
__global__ __launch_bounds__(256) void gemm2_k(
    const short* __restrict__ A, const short* __restrict__ B,
    const float* __restrict__ bias, void* __restrict__ out0,
    short* __restrict__ outT, int M, int N, int K, int out_ld) {
    __shared__ short As[128 * 64];
    __shared__ short Bs[128 * 64];
    const int tid = threadIdx.x;
    const int lane = tid & 63, wave = tid >> 6;
    const int g = lane >> 4, c = lane & 15;
    const int nbm = M >> 7;
    const int x = blockIdx.x & 7, j = blockIdx.x >> 3;
    const int bm = x * (nbm >> 3) + (j >> 3);
    const int bn = j & 7;
    const int wr = wave >> 1, wc = wave & 1;

    const int srow = lane >> 3, scol = (lane & 7) * 8;
    const short* ag = A + (size_t)(bm * 128 + wave * 32 + srow) * K + scol;
    const short* bg = B + (size_t)(bn * 128 + wave * 32 + srow) * K + scol;

    f32x4 acc[4][4] = {};
    for (int k0 = 0; k0 < K; k0 += 64) {
#pragma unroll
        for (int ch = 0; ch < 4; ++ch) {
            gld16(ag + (size_t)(ch * 8) * K + k0, As + (wave * 32 + ch * 8) * 64);
            gld16(bg + (size_t)(ch * 8) * K + k0, Bs + (wave * 32 + ch * 8) * 64);
        }
        __syncthreads();
#pragma unroll
        for (int ks = 0; ks < 2; ++ks) {
            short8 af[4], bfr[4];
#pragma unroll
            for (int mi = 0; mi < 4; ++mi) af[mi] = *(const short8*)(As + (wr * 64 + mi * 16 + c) * 64 + ks * 32 + g * 8);
#pragma unroll
            for (int ni = 0; ni < 4; ++ni) bfr[ni] = *(const short8*)(Bs + (wc * 64 + ni * 16 + c) * 64 + ks * 32 + g * 8);
#pragma unroll
            for (int mi = 0; mi < 4; ++mi)
#pragma unroll
                for (int ni = 0; ni < 4; ++ni)
                    acc[mi][ni] = __builtin_amdgcn_mfma_f32_16x16x32_bf16(af[mi], bfr[ni], acc[mi][ni], 0, 0, 0);
        }
        __syncthreads();
    }

    const int m0 = bm * 128 + wr * 64, n0 = bn * 128 + wc * 64;
#pragma unroll
    for (int ni = 0; ni < 4; ++ni) {
        int n = n0 + ni * 16 + c;
        float bn_ = bias[n];
#pragma unroll
        for (int mi = 0; mi < 4; ++mi) {
            int mb = m0 + mi * 16 + 4 * g;
            f32x4 v = acc[mi][ni];
            if constexpr (MODE == 2) {
                float* o = (float*)out0;
#pragma unroll
                for (int r = 0; r < 4; ++r)
                    o[(size_t)(mb + r) * out_ld + n] = tanhf(v[r] + bn_);
            } else {
                short* o = (short*)out0;
                short4v pk;
#pragma unroll
                for (int r = 0; r < 4; ++r) {
                    pk[r] = f2bf(v[r] + bn_);
                    o[(size_t)(mb + r) * out_ld + n] = pk[r];
                }
                if constexpr (MODE == 0) {
                    int h = n >> 7, hd = n & 127;
                    int bb = mb >> 11, vv = mb & 2047;
                    *(short4v*)(outT + ((size_t)((bb * NH + h) * DH + hd)) * VL + vv) = pk;
                }
            }
        }
    }
}

// ---------- rowsum kernel (round-7 4-wave form) ----------
__global__ __launch_bounds__(256) void rowsum_k(
    const short* __restrict__ qs, const short* __restrict__ vs,
    float* __restrict__ rsum_part) {
    __shared__ short As[128 * 64];
    __shared__ short Bs[128 * 64];
    const int blk = blockIdx.x;
    const int xr = blk & 7, t = blk >> 3;
    const int bn = t & 15;
    const int bm = (t >> 4) & 3;
    const int bh = ((t >> 6) << 3) | xr;
    const int h = bh & 7, b = bh >> 3;

    const int tid = threadIdx.x;
    const int lane = tid & 63, wave = tid >> 6;
    const int g = lane >> 4, c = lane & 15;
    const int wr = wave >> 1, wc = wave & 1;
    const float sc = 0.08838834764831845f;   // 1/sqrt(128)

    const int srow = lane >> 3, scol = (lane & 7) * 8;
    const short* ag = qs + (size_t)(b * QL + bm * 128 + wave * 32 + srow) * DM + h * DH + scol;
    const short* bg = vs + (size_t)(b * VL + bn * 128 + wave * 32 + srow) * DM + h * DH + scol;

    f32x4 acc[4][4] = {};
    for (int k0 = 0; k0 < DH; k0 += 64) {
#pragma unroll
        for (int ch = 0; ch < 4; ++ch) {
            gld16(ag + (size_t)(ch * 8) * DM + k0, As + (wave * 32 + ch * 8) * 64);
            gld16(bg + (size_t)(ch * 8) * DM + k0, Bs + (wave * 32 + ch * 8) * 64);
        }
        __syncthreads();
#pragma unroll
        for (int ks = 0; ks < 2; ++ks) {
            short8 af[4], bfr[4];
#pragma unroll
            for (int mi = 0; mi < 4; ++mi) af[mi] = *(const short8*)(As + (wr * 64 + mi * 16 + c) * 64 + ks * 32 + g * 8);
#pragma unroll
            for (int ni = 0; ni < 4; ++ni) bfr[ni] = *(const short8*)(Bs + (wc * 64 + ni * 16 + c) * 64 + ks * 32 + g * 8);
#pragma unroll
            for (int mi = 0; mi < 4; ++mi)
#pragma unroll
                for (int ni = 0; ni < 4; ++ni)
                    acc[mi][ni] = __builtin_amdgcn_mfma_f32_16x16x32_bf16(af[mi], bfr[ni], acc[mi][ni], 0, 0, 0);
        }
        __syncthreads();
    }

    float psum[4][4];
#pragma unroll
    for (int mi = 0; mi < 4; ++mi)
#pragma unroll
        for (int r = 0; r < 4; ++r) psum[mi][r] = 0.f;

    const int m0 = bm * 128 + wr * 64;
#pragma unroll
    for (int ni = 0; ni < 4; ++ni) {
#pragma unroll
        for (int mi = 0; mi < 4; ++mi) {
            f32x4 v = acc[mi][ni];
#pragma unroll
            for (int r = 0; r < 4; ++r)
                psum[mi][r] += __builtin_amdgcn_rcpf(1.f + __expf(-v[r] * sc));
        }
    }
#pragma unroll
    for (int off = 1; off < 16; off <<= 1)
#pragma unroll
        for (int mi = 0; mi < 4; ++mi)
#pragma unroll
            for (int r = 0; r < 4; ++r) psum[mi][r] += __shfl_xor(psum[mi][r], off);
    if (c == 0) {
#pragma unroll
        for (int mi = 0; mi < 4; ++mi)
#pragma unroll
            for (int r = 0; r < 4; ++r) {
                int q = m0 + mi * 16 + 4 * g + r;
                rsum_part[(size_t)(bh * QL + q) * 32 + bn * 2 + wc] = psum[mi][r];
            }
    }
}

// ---------- fused attention kernel, V-split, PV-from-L2 ----------
// Block = (bh, 64-q tile, v-half); 4 waves x 16 q-rows; 16 chunks of 64 v.
// Vs staged reg->LDS (T14 prefetch); PV B-fragments read directly from
// global (L2-resident vsT slice). LDS ~27KB -> 4-5 blocks/CU.
__global__ __launch_bounds__(256, 4) void fat2_k(
    const short* __restrict__ qs, const short* __restrict__ vs,
    const short* __restrict__ vsT, const float* __restrict__ rsum_part,
    float* __restrict__ align_out, float* __restrict__ ctxp) {
    __shared__ short Vs[64][136];
    __shared__ short Pl[4][16][72];
    __shared__ float rsl[64];

    const int blk = blockIdx.x;          // 1024; phys%8 groups bh on one XCD
    const int xr = blk & 7, t = blk >> 3;
    const int vh = t & 1;
    const int qt = (t >> 1) & 7;
    const int bh = ((t >> 4) << 3) | xr;
    const int h = bh & 7, b = bh >> 3;
    const int q0 = qt * 64;
    const int vbeg = vh * 1024;

    const int tid = threadIdx.x, wave = tid >> 6, lane = tid & 63;
    const int g = lane >> 4, c = lane & 15;
    const float sc = 0.08838834764831845f;      // 1/sqrt(128)

    if (tid < 64) {
        const float* p = rsum_part + (size_t)(bh * QL + q0 + tid) * 32;
        float s = 0.f;
#pragma unroll
        for (int jj = 0; jj < 32; ++jj) s += p[jj];
        rsl[tid] = __builtin_amdgcn_rcpf(s);
    }
    __syncthreads();

    float invr[4];
#pragma unroll
    for (int r = 0; r < 4; ++r) invr[r] = rsl[wave * 16 + 4 * g + r];

    // Q fragments (one-time, 16 rows x 128 d per wave)
    short8 qa[4];
    const short* qb = qs + ((size_t)(b * QL + q0 + wave * 16 + c)) * DM + h * DH + g * 8;
#pragma unroll
    for (int ks = 0; ks < 4; ++ks) qa[ks] = *(const short8*)(qb + ks * 32);

    // Vs staging base (QK operand)
    const int vsrow = tid >> 2, vscq = (tid & 3) * 32;
    const short* vsg = vs + ((size_t)(b * VL + vsrow)) * DM + h * DH + vscq;
    // PV fragment base (direct global/L2)
    const short* vtb = vsT + ((size_t)(bh * DH + c)) * VL + g * 8;

    float* ao = align_out + ((size_t)((h * NB + b) * QL + q0 + wave * 16)) * VL;

    // prologue: load chunk 0 into regs
    short8 pv_s[4];
#pragma unroll
    for (int i = 0; i < 4; ++i) pv_s[i] = *(const short8*)(vsg + (size_t)vbeg * DM + i * 8);

    f32x4 ctx[8] = {};
    for (int tc = 0; tc < 16; ++tc) {
        const int v0 = vbeg + tc * 64;
        // write staged regs to LDS
#pragma unroll
        for (int i = 0; i < 4; ++i) *(short8*)&Vs[vsrow][vscq + i * 8] = pv_s[i];
        __syncthreads();
        // T14: issue next chunk's loads early (hide under compute)
        if (tc + 1 < 16) {
            const int v1 = v0 + 64;
#pragma unroll
            for (int i = 0; i < 4; ++i) pv_s[i] = *(const short8*)(vsg + (size_t)v1 * DM + i * 8);
        }

        // QK: S chunk 16q x 64v per wave
#pragma unroll
        for (int ni = 0; ni < 4; ++ni) {
            f32x4 s = {0.f, 0.f, 0.f, 0.f};
#pragma unroll
            for (int ks = 0; ks < 4; ++ks)
                s = __builtin_amdgcn_mfma_f32_16x16x32_bf16(qa[ks], *(const short8*)&Vs[ni * 16 + c][ks * 32 + g * 8], s, 0, 0, 0);
#pragma unroll
            for (int r = 0; r < 4; ++r) {
                float pn = __builtin_amdgcn_rcpf(1.f + __expf(-s[r] * sc)) * invr[r];
                __builtin_nontemporal_store(pn, &ao[(size_t)(4 * g + r) * VL + v0 + ni * 16 + c]);
                Pl[wave][4 * g + r][ni * 16 + c] = f2bf(pn);
            }
        }
        __syncthreads();   // all waves done reading Vs; PV below doesn't touch Vs

        // PV: ctx += P_chunk @ Vt_chunk^T, B-fragments straight from L2
        short8 pa0 = *(const short8*)&Pl[wave][c][g * 8];
        short8 pa1 = *(const short8*)&Pl[wave][c][32 + g * 8];
#pragma unroll
        for (int df = 0; df < 8; ++df) {
            const short* tb = vtb + (size_t)(df * 16) * VL + v0;
            ctx[df] = __builtin_amdgcn_mfma_f32_16x16x32_bf16(pa0, *(const short8*)(tb), ctx[df], 0, 0, 0);
            ctx[df] = __builtin_amdgcn_mfma_f32_16x16x32_bf16(pa1, *(const short8*)(tb + 32), ctx[df], 0, 0, 0);
        }
    }

    // store partial ctx (f32) to scratch
    float* cp = ctxp + ((size_t)((bh * 8 + qt) * 2 + vh)) * (64 * 128);
#pragma unroll
    for (int df = 0; df < 8; ++df)
#pragma unroll
        for (int r = 0; r < 4; ++r)
            cp[(size_t)(wave * 16 + 4 * g + r) * 128 + df * 16 + c] = ctx[df][r];
}

// ---------- ctx reduce: comb ctx half = bf16(part0 + part1) ----------
__global__ void ctxred_k(const float* __restrict__ ctxp, short* __restrict__ comb) {
    int id = blockIdx.x * 256 + threadIdx.x;   // 524288 ids, 8 elems each
    int d0 = (id & 15) * 8;
    int r  = (id >> 4) & 63;
    int qt = (id >> 10) & 7;
    int bh = id >> 13;
    int h = bh & 7, b = bh >> 3;
    const float* p0 = ctxp + ((size_t)((bh * 8 + qt) * 2)) * 8192 + r * 128 + d0;
    const float* p1 = p0 + 8192;
    short8 o;
#pragma unroll
    for (int jj = 0; jj < 8; ++jj) o[jj] = f2bf(p0[jj] + p1[jj]);
    *(short8*)(comb + ((size_t)(b * QL + qt * 64 + r)) * (2 * DM) + h * DH + d0) = o;
}

// ---------- launch ----------
extern "C" void kernel_launch(void* const* d_in, const int* in_sizes, int n_in,
                              void* d_out, int out_size, void* d_ws, size_t ws_size,
                              hipStream_t stream) {
    (void)in_sizes; (void)n_in; (void)out_size; (void)ws_size;
    const float* Q    = (const float*)d_in[0];
    const float* V    = (const float*)d_in[1];
    const float* la   = (const float*)d_in[2];
    const float* cw   = (const float*)d_in[3];
    const float* cb   = (const float*)d_in[4];
    const float* Wq   = (const float*)d_in[5];
    const float* bq   = (const float*)d_in[6];
    const float* Wv   = (const float*)d_in[7];
    const float* bv   = (const float*)d_in[8];
    const float* Wu   = (const float*)d_in[9];
    const float* bu   = (const float*)d_in[10];
    const float* bias = (const float*)d_in[11];
    const float* fcw  = (const float*)d_in[12];
    const float* fcb  = (const float*)d_in[13];

    float* out = (float*)d_out;
    float* align_out = out + (size_t)NB * QL * DM;

    char* w = (char*)d_ws;
    short* Vb   = (short*)w; w += (size_t)16384 * 1024 * 2;      // 32 MB
    short* Aq   = (short*)w; w += (size_t)4096 * KQ * 2;         // 8.9 MB
    short* comb = (short*)w; w += (size_t)4096 * 2048 * 2;       // 16 MB
    short* Bq   = (short*)w; w += (size_t)1024 * KQ * 2;         // 2.2 MB
    short* Bvw  = (short*)w; w += (size_t)1024 * 1024 * 2;       // 2 MB
    short* Bfc  = (short*)w; w += (size_t)1024 * 2048 * 2;       // 4 MB
    short* vsb  = (short*)w; w += (size_t)16384 * 1024 * 2;      // 32 MB
    short* vsT  = (short*)w; w += (size_t)16384 * 1024 * 2;      // 32 MB
    short* qsb  = (short*)w; w += (size_t)4096 * 1024 * 2;       // 8 MB
    float* rsum_part = (float*)w; w += (size_t)32768 * 32 * 4;   // 4 MB
    float* ctxp = (float*)w; w += (size_t)1024 * 64 * 128 * 4;   // 32 MB
    float* cbias = (float*)w; w += 1024 * 4;

    // all prep in one launch (ranges: cbias|conv|castq|castv|buildw) — 26900 blocks
    prep_k<<<26900, 256, 0, stream>>>(Q, V, la, cw, cb, Wq, bq, Wv, Wu, bu, bias, fcw,
                                      cbias, Aq, comb, Vb, Bq, Bvw, Bfc);
    // v_s = V @ Wv^T + bv  (+ transposed copy per head)
    gemm2_k<0><<<1024, 256, 0, stream>>>(Vb, Bvw, bv, vsb, vsT, 16384, 1024, 1024, 1024);
    // q_s = [Q|U] @ [Wq|Wu]^T + (bq+bu+bias)
    gemm2_k<1><<<256, 256, 0, stream>>>(Aq, Bq, cbias, qsb, nullptr, 4096, 1024, KQ, 1024);
    // attention: rowsum pre-pass, then fused V-split QK/sigmoid/align/PV, then ctx reduce
    rowsum_k<<<4096, 256, 0, stream>>>(qsb, vsb, rsum_part);
    fat2_k<<<1024, 256, 0, stream>>>(qsb, vsb, vsT, rsum_part, align_out, ctxp);
    ctxred_k<<<2048, 256, 0, stream>>>(ctxp, comb);
    // output = tanh(combined @ fc_w^T + fc_b)
    gemm2_k<2><<<256, 256, 0, stream>>>(comb, Bfc, fcb, out, nullptr, 4096, 1024, 2048, 1024);
}

// Round 10
// 326.240 us; speedup vs baseline: 1.1334x; 1.1334x over previous
//
#include <hip/hip_runtime.h>

// ---------- types ----------
typedef __attribute__((ext_vector_type(8))) short short8;
typedef __attribute__((ext_vector_type(4))) short short4v;
typedef __attribute__((ext_vector_type(4))) float f32x4;

static __device__ __forceinline__ short f2bf(float x) {
    unsigned u = __builtin_bit_cast(unsigned, x);
    unsigned r = (u + 0x7fffu + ((u >> 16) & 1u)) >> 16;
    return (short)r;
}

// async global->LDS, 16B per lane: lds dest = uniform base + lane*16
static __device__ __forceinline__ void gld16(const short* g, short* l) {
    __builtin_amdgcn_global_load_lds((const __attribute__((address_space(1))) void*)g,
                                     (__attribute__((address_space(3))) void*)l, 16, 0, 0);
}

#define QL 512
#define VL 2048
#define DM 1024
#define NH 8
#define DH 128
#define NB 8
#define KQ 1088   // 1024 + 64 (U columns padded)

// ---------- merged prep kernel ----------
// ranges: [0,4) cbias | [4,20) conv | [20,2068) castq | [2068,10260) castv | [10260,26900) buildw
__global__ void prep_k(const float* __restrict__ Q, const float* __restrict__ V,
                       const float* __restrict__ la, const float* __restrict__ cw,
                       const float* __restrict__ cb,
                       const float* __restrict__ Wq, const float* __restrict__ bq,
                       const float* __restrict__ Wv, const float* __restrict__ Wu,
                       const float* __restrict__ bu, const float* __restrict__ bias,
                       const float* __restrict__ fcw,
                       float* __restrict__ cbias, short* __restrict__ Aq,
                       short* __restrict__ comb, short* __restrict__ Vb,
                       short* __restrict__ Bq, short* __restrict__ Bv,
                       short* __restrict__ Bfc) {
    const int blk = blockIdx.x, tid = threadIdx.x;
    if (blk < 4) {
        int i = blk * 256 + tid;
        if (i < DM) cbias[i] = bq[i] + bu[i] + bias[i];
    } else if (blk < 20) {
        int m = (blk - 4) * 256 + tid;
        if (m >= NB * QL) return;
        int b = m >> 9, t = m & 511;
        const float* l = la + b * QL;
        float lm = (t > 0)      ? l[t - 1] : 0.f;
        float l0 = l[t];
        float lp = (t < QL - 1) ? l[t + 1] : 0.f;
        short* row = Aq + (size_t)m * KQ + 1024;
#pragma unroll
        for (int k = 0; k < 10; ++k)
            row[k] = f2bf(cb[k] + lm * cw[k * 3 + 0] + l0 * cw[k * 3 + 1] + lp * cw[k * 3 + 2]);
        for (int k = 10; k < 64; ++k) row[k] = 0;
    } else if (blk < 2068) {
        int id = (blk - 20) * 256 + tid;
        int m = id >> 7, kc = (id & 127) * 8;
        const float* p = Q + (size_t)m * DM + kc;
        float4 f0 = *(const float4*)p;
        float4 f1 = *(const float4*)(p + 4);
        short8 v;
        v[0]=f2bf(f0.x); v[1]=f2bf(f0.y); v[2]=f2bf(f0.z); v[3]=f2bf(f0.w);
        v[4]=f2bf(f1.x); v[5]=f2bf(f1.y); v[6]=f2bf(f1.z); v[7]=f2bf(f1.w);
        *(short8*)(Aq + (size_t)m * KQ + kc) = v;
        *(short8*)(comb + (size_t)m * (2 * DM) + DM + kc) = v;
    } else if (blk < 10260) {
        int id = (blk - 2068) * 256 + tid;
        const float* p = V + (size_t)id * 8;
        float4 f0 = *(const float4*)p;
        float4 f1 = *(const float4*)(p + 4);
        short8 v;
        v[0]=f2bf(f0.x); v[1]=f2bf(f0.y); v[2]=f2bf(f0.z); v[3]=f2bf(f0.w);
        v[4]=f2bf(f1.x); v[5]=f2bf(f1.y); v[6]=f2bf(f1.z); v[7]=f2bf(f1.w);
        *(short8*)(Vb + (size_t)id * 8) = v;
    } else {
        int id = (blk - 10260) * 256 + tid;
        const int nq = DM * KQ;             // 1,114,112
        const int nv = DM * DM;             // 1,048,576
        const int nf = DM * 2 * DM;         // 2,097,152  -> total 16640 blocks
        if (id < nq) {
            int n = id / KQ, k = id % KQ;
            float v = (k < 1024) ? Wq[(size_t)n * 1024 + k]
                                 : ((k < 1034) ? Wu[n * 10 + (k - 1024)] : 0.f);
            Bq[id] = f2bf(v);
        } else if (id < nq + nv) {
            int j = id - nq;
            Bv[j] = f2bf(Wv[j]);
        } else if (id < nq + nv + nf) {
            int j = id - nq - nv;
            Bfc[j] = f2bf(fcw[j]);
        }
    }
}

// ---------- m97-style MFMA GEMM (4-wave, round-7 measured form) ----------
// MODE 0: v_s — bf16 out + transposed out; MODE 1: q_s — bf16 out; MODE 2: fc — f32 tanh
template <int MODE>
__global__ __launch_bounds__(256) void gemm2_k(
    const short* __restrict__ A, const short* __restrict__ B,
    const float* __restrict__ bias, void* __restrict__ out0,
    short* __restrict__ outT, int M, int N, int K, int out_ld) {
    __shared__ short As[128 * 64];
    __shared__ short Bs[128 * 64];
    const int tid = threadIdx.x;
    const int lane = tid & 63, wave = tid >> 6;
    const int g = lane >> 4, c = lane & 15;
    const int nbm = M >> 7;
    const int x = blockIdx.x & 7, j = blockIdx.x >> 3;
    const int bm = x * (nbm >> 3) + (j >> 3);
    const int bn = j & 7;
    const int wr = wave >> 1, wc = wave & 1;

    const int srow = lane >> 3, scol = (lane & 7) * 8;
    const short* ag = A + (size_t)(bm * 128 + wave * 32 + srow) * K + scol;
    const short* bg = B + (size_t)(bn * 128 + wave * 32 + srow) * K + scol;

    f32x4 acc[4][4] = {};
    for (int k0 = 0; k0 < K; k0 += 64) {
#pragma unroll
        for (int ch = 0; ch < 4; ++ch) {
            gld16(ag + (size_t)(ch * 8) * K + k0, As + (wave * 32 + ch * 8) * 64);
            gld16(bg + (size_t)(ch * 8) * K + k0, Bs + (wave * 32 + ch * 8) * 64);
        }
        __syncthreads();
#pragma unroll
        for (int ks = 0; ks < 2; ++ks) {
            short8 af[4], bfr[4];
#pragma unroll
            for (int mi = 0; mi < 4; ++mi) af[mi] = *(const short8*)(As + (wr * 64 + mi * 16 + c) * 64 + ks * 32 + g * 8);
#pragma unroll
            for (int ni = 0; ni < 4; ++ni) bfr[ni] = *(const short8*)(Bs + (wc * 64 + ni * 16 + c) * 64 + ks * 32 + g * 8);
#pragma unroll
            for (int mi = 0; mi < 4; ++mi)
#pragma unroll
                for (int ni = 0; ni < 4; ++ni)
                    acc[mi][ni] = __builtin_amdgcn_mfma_f32_16x16x32_bf16(af[mi], bfr[ni], acc[mi][ni], 0, 0, 0);
        }
        __syncthreads();
    }

    const int m0 = bm * 128 + wr * 64, n0 = bn * 128 + wc * 64;
#pragma unroll
    for (int ni = 0; ni < 4; ++ni) {
        int n = n0 + ni * 16 + c;
        float bn_ = bias[n];
#pragma unroll
        for (int mi = 0; mi < 4; ++mi) {
            int mb = m0 + mi * 16 + 4 * g;
            f32x4 v = acc[mi][ni];
            if constexpr (MODE == 2) {
                float* o = (float*)out0;
#pragma unroll
                for (int r = 0; r < 4; ++r)
                    o[(size_t)(mb + r) * out_ld + n] = tanhf(v[r] + bn_);
            } else {
                short* o = (short*)out0;
                short4v pk;
#pragma unroll
                for (int r = 0; r < 4; ++r) {
                    pk[r] = f2bf(v[r] + bn_);
                    o[(size_t)(mb + r) * out_ld + n] = pk[r];
                }
                if constexpr (MODE == 0) {
                    int h = n >> 7, hd = n & 127;
                    int bb = mb >> 11, vv = mb & 2047;
                    *(short4v*)(outT + ((size_t)((bb * NH + h) * DH + hd)) * VL + vv) = pk;
                }
            }
        }
    }
}

// ---------- rowsum kernel (4-wave, round-7 measured form) ----------
__global__ __launch_bounds__(256) void rowsum_k(
    const short* __restrict__ qs, const short* __restrict__ vs,
    float* __restrict__ rsum_part) {
    __shared__ short As[128 * 64];
    __shared__ short Bs[128 * 64];
    const int blk = blockIdx.x;
    const int xr = blk & 7, t = blk >> 3;
    const int bn = t & 15;
    const int bm = (t >> 4) & 3;
    const int bh = ((t >> 6) << 3) | xr;
    const int h = bh & 7, b = bh >> 3;

    const int tid = threadIdx.x;
    const int lane = tid & 63, wave = tid >> 6;
    const int g = lane >> 4, c = lane & 15;
    const int wr = wave >> 1, wc = wave & 1;
    const float sc = 0.08838834764831845f;   // 1/sqrt(128)

    const int srow = lane >> 3, scol = (lane & 7) * 8;
    const short* ag = qs + (size_t)(b * QL + bm * 128 + wave * 32 + srow) * DM + h * DH + scol;
    const short* bg = vs + (size_t)(b * VL + bn * 128 + wave * 32 + srow) * DM + h * DH + scol;

    f32x4 acc[4][4] = {};
    for (int k0 = 0; k0 < DH; k0 += 64) {
#pragma unroll
        for (int ch = 0; ch < 4; ++ch) {
            gld16(ag + (size_t)(ch * 8) * DM + k0, As + (wave * 32 + ch * 8) * 64);
            gld16(bg + (size_t)(ch * 8) * DM + k0, Bs + (wave * 32 + ch * 8) * 64);
        }
        __syncthreads();
#pragma unroll
        for (int ks = 0; ks < 2; ++ks) {
            short8 af[4], bfr[4];
#pragma unroll
            for (int mi = 0; mi < 4; ++mi) af[mi] = *(const short8*)(As + (wr * 64 + mi * 16 + c) * 64 + ks * 32 + g * 8);
#pragma unroll
            for (int ni = 0; ni < 4; ++ni) bfr[ni] = *(const short8*)(Bs + (wc * 64 + ni * 16 + c) * 64 + ks * 32 + g * 8);
#pragma unroll
            for (int mi = 0; mi < 4; ++mi)
#pragma unroll
                for (int ni = 0; ni < 4; ++ni)
                    acc[mi][ni] = __builtin_amdgcn_mfma_f32_16x16x32_bf16(af[mi], bfr[ni], acc[mi][ni], 0, 0, 0);
        }
        __syncthreads();
    }

    float psum[4][4];
#pragma unroll
    for (int mi = 0; mi < 4; ++mi)
#pragma unroll
        for (int r = 0; r < 4; ++r) psum[mi][r] = 0.f;

    const int m0 = bm * 128 + wr * 64;
#pragma unroll
    for (int ni = 0; ni < 4; ++ni) {
#pragma unroll
        for (int mi = 0; mi < 4; ++mi) {
            f32x4 v = acc[mi][ni];
#pragma unroll
            for (int r = 0; r < 4; ++r)
                psum[mi][r] += __builtin_amdgcn_rcpf(1.f + __expf(-v[r] * sc));
        }
    }
#pragma unroll
    for (int off = 1; off < 16; off <<= 1)
#pragma unroll
        for (int mi = 0; mi < 4; ++mi)
#pragma unroll
            for (int r = 0; r < 4; ++r) psum[mi][r] += __shfl_xor(psum[mi][r], off);
    if (c == 0) {
#pragma unroll
        for (int mi = 0; mi < 4; ++mi)
#pragma unroll
            for (int r = 0; r < 4; ++r) {
                int q = m0 + mi * 16 + 4 * g + r;
                rsum_part[(size_t)(bh * QL + q) * 32 + bn * 2 + wc] = psum[mi][r];
            }
    }
}

// ---------- fused attention kernel: 8 waves, 128 q-rows, V-split ----------
// Block = (bh, 128-q tile, v-half); 8 waves x 16 q-rows; 16 chunks of 64 v.
// Vs+Vt staged reg->LDS with T14 prefetch; 2x MFMA per staged chunk vs r7.
__global__ __launch_bounds__(512, 6) void fat2_k(
    const short* __restrict__ qs, const short* __restrict__ vs,
    const short* __restrict__ vsT, const float* __restrict__ rsum_part,
    float* __restrict__ align_out, float* __restrict__ ctxp) {
    __shared__ short Vs[64][132];
    __shared__ short Vt[128][70];
    __shared__ short Pl[8][16][68];
    __shared__ float rsl[128];

    const int blk = blockIdx.x;          // 512; phys%8 groups bh on one XCD
    const int xr = blk & 7, t = blk >> 3;
    const int vh = t & 1;
    const int qt = (t >> 1) & 3;         // 4 q-tiles of 128
    const int bh = ((t >> 3) << 3) | xr;
    const int h = bh & 7, b = bh >> 3;
    const int q0 = qt * 128;
    const int vbeg = vh * 1024;

    const int tid = threadIdx.x, wave = tid >> 6, lane = tid & 63;
    const int g = lane >> 4, c = lane & 15;
    const float sc = 0.08838834764831845f;      // 1/sqrt(128)

    if (tid < 128) {
        const float* p = rsum_part + (size_t)(bh * QL + q0 + tid) * 32;
        float s = 0.f;
#pragma unroll
        for (int jj = 0; jj < 32; ++jj) s += p[jj];
        rsl[tid] = __builtin_amdgcn_rcpf(s);
    }
    __syncthreads();

    float invr[4];
#pragma unroll
    for (int r = 0; r < 4; ++r) invr[r] = rsl[wave * 16 + 4 * g + r];

    // Q fragments (one-time, 16 rows x 128 d per wave)
    short8 qa[4];
    const short* qb = qs + ((size_t)(b * QL + q0 + wave * 16 + c)) * DM + h * DH + g * 8;
#pragma unroll
    for (int ks = 0; ks < 4; ++ks) qa[ks] = *(const short8*)(qb + ks * 32);

    // staging bases (512 threads: Vs 64x128 -> 16 shorts/thread; Vt 128x64 -> 16)
    const int vsrow = tid >> 3, vscq = (tid & 7) * 16;
    const short* vsg = vs + ((size_t)(b * VL + vsrow)) * DM + h * DH + vscq;
    const int vtrow = tid >> 2, vtcq = (tid & 3) * 16;
    const short* vtg = vsT + ((size_t)(bh * DH + vtrow)) * VL + vtcq;

    float* ao = align_out + ((size_t)((h * NB + b) * QL + q0 + wave * 16)) * VL;

    // prologue: load chunk 0 into regs
    short8 pv_s[2], pv_t[2];
#pragma unroll
    for (int i = 0; i < 2; ++i) pv_s[i] = *(const short8*)(vsg + (size_t)vbeg * DM + i * 8);
#pragma unroll
    for (int i = 0; i < 2; ++i) pv_t[i] = *(const short8*)(vtg + vbeg + i * 8);

    f32x4 ctx[8] = {};
    for (int tc = 0; tc < 16; ++tc) {
        const int v0 = vbeg + tc * 64;
        // write staged regs to LDS
#pragma unroll
        for (int i = 0; i < 2; ++i) *(short8*)&Vs[vsrow][vscq + i * 8] = pv_s[i];
#pragma unroll
        for (int i = 0; i < 2; ++i) *(short8*)&Vt[vtrow][vtcq + i * 8] = pv_t[i];
        __syncthreads();
        // T14: issue next chunk's loads early (hide under compute)
        if (tc + 1 < 16) {
            const int v1 = v0 + 64;
#pragma unroll
            for (int i = 0; i < 2; ++i) pv_s[i] = *(const short8*)(vsg + (size_t)v1 * DM + i * 8);
#pragma unroll
            for (int i = 0; i < 2; ++i) pv_t[i] = *(const short8*)(vtg + v1 + i * 8);
        }

        // QK: S chunk 16q x 64v per wave
#pragma unroll
        for (int ni = 0; ni < 4; ++ni) {
            f32x4 s = {0.f, 0.f, 0.f, 0.f};
#pragma unroll
            for (int ks = 0; ks < 4; ++ks)
                s = __builtin_amdgcn_mfma_f32_16x16x32_bf16(qa[ks], *(const short8*)&Vs[ni * 16 + c][ks * 32 + g * 8], s, 0, 0, 0);
#pragma unroll
            for (int r = 0; r < 4; ++r) {
                float pn = __builtin_amdgcn_rcpf(1.f + __expf(-s[r] * sc)) * invr[r];
                __builtin_nontemporal_store(pn, &ao[(size_t)(4 * g + r) * VL + v0 + ni * 16 + c]);
                Pl[wave][4 * g + r][ni * 16 + c] = f2bf(pn);
            }
        }
        // PV: ctx += P_chunk @ Vt_chunk^T
        short8 pa0 = *(const short8*)&Pl[wave][c][g * 8];
        short8 pa1 = *(const short8*)&Pl[wave][c][32 + g * 8];
#pragma unroll
        for (int df = 0; df < 8; ++df) {
            ctx[df] = __builtin_amdgcn_mfma_f32_16x16x32_bf16(pa0, *(const short8*)&Vt[df * 16 + c][g * 8], ctx[df], 0, 0, 0);
            ctx[df] = __builtin_amdgcn_mfma_f32_16x16x32_bf16(pa1, *(const short8*)&Vt[df * 16 + c][32 + g * 8], ctx[df], 0, 0, 0);
        }
        __syncthreads();
    }

    // store partial ctx (f32) to scratch: tile is 128 q-rows x 128 d
    float* cp = ctxp + ((size_t)((bh * 4 + qt) * 2 + vh)) * (128 * 128);
#pragma unroll
    for (int df = 0; df < 8; ++df)
#pragma unroll
        for (int r = 0; r < 4; ++r)
            cp[(size_t)(wave * 16 + 4 * g + r) * 128 + df * 16 + c] = ctx[df][r];
}

// ---------- ctx reduce: comb ctx half = bf16(part0 + part1) ----------
__global__ void ctxred_k(const float* __restrict__ ctxp, short* __restrict__ comb) {
    int id = blockIdx.x * 256 + threadIdx.x;   // 524288 ids, 8 elems each
    int d0 = (id & 15) * 8;
    int r  = (id >> 4) & 127;
    int qt = (id >> 11) & 3;
    int bh = id >> 13;
    int h = bh & 7, b = bh >> 3;
    const float* p0 = ctxp + ((size_t)((bh * 4 + qt) * 2)) * 16384 + r * 128 + d0;
    const float* p1 = p0 + 16384;
    short8 o;
#pragma unroll
    for (int jj = 0; jj < 8; ++jj) o[jj] = f2bf(p0[jj] + p1[jj]);
    *(short8*)(comb + ((size_t)(b * QL + qt * 128 + r)) * (2 * DM) + h * DH + d0) = o;
}

// ---------- launch ----------
extern "C" void kernel_launch(void* const* d_in, const int* in_sizes, int n_in,
                              void* d_out, int out_size, void* d_ws, size_t ws_size,
                              hipStream_t stream) {
    (void)in_sizes; (void)n_in; (void)out_size; (void)ws_size;
    const float* Q    = (const float*)d_in[0];
    const float* V    = (const float*)d_in[1];
    const float* la   = (const float*)d_in[2];
    const float* cw   = (const float*)d_in[3];
    const float* cb   = (const float*)d_in[4];
    const float* Wq   = (const float*)d_in[5];
    const float* bq   = (const float*)d_in[6];
    const float* Wv   = (const float*)d_in[7];
    const float* bv   = (const float*)d_in[8];
    const float* Wu   = (const float*)d_in[9];
    const float* bu   = (const float*)d_in[10];
    const float* bias = (const float*)d_in[11];
    const float* fcw  = (const float*)d_in[12];
    const float* fcb  = (const float*)d_in[13];

    float* out = (float*)d_out;
    float* align_out = out + (size_t)NB * QL * DM;

    char* w = (char*)d_ws;
    short* Vb   = (short*)w; w += (size_t)16384 * 1024 * 2;      // 32 MB
    short* Aq   = (short*)w; w += (size_t)4096 * KQ * 2;         // 8.9 MB
    short* comb = (short*)w; w += (size_t)4096 * 2048 * 2;       // 16 MB
    short* Bq   = (short*)w; w += (size_t)1024 * KQ * 2;         // 2.2 MB
    short* Bvw  = (short*)w; w += (size_t)1024 * 1024 * 2;       // 2 MB
    short* Bfc  = (short*)w; w += (size_t)1024 * 2048 * 2;       // 4 MB
    short* vsb  = (short*)w; w += (size_t)16384 * 1024 * 2;      // 32 MB
    short* vsT  = (short*)w; w += (size_t)16384 * 1024 * 2;      // 32 MB
    short* qsb  = (short*)w; w += (size_t)4096 * 1024 * 2;       // 8 MB
    float* rsum_part = (float*)w; w += (size_t)32768 * 32 * 4;   // 4 MB
    float* ctxp = (float*)w; w += (size_t)512 * 128 * 128 * 4;   // 32 MB
    float* cbias = (float*)w; w += 1024 * 4;

    // all prep in one launch (ranges: cbias|conv|castq|castv|buildw) — 26900 blocks
    prep_k<<<26900, 256, 0, stream>>>(Q, V, la, cw, cb, Wq, bq, Wv, Wu, bu, bias, fcw,
                                      cbias, Aq, comb, Vb, Bq, Bvw, Bfc);
    // v_s = V @ Wv^T + bv  (+ transposed copy per head)
    gemm2_k<0><<<1024, 256, 0, stream>>>(Vb, Bvw, bv, vsb, vsT, 16384, 1024, 1024, 1024);
    // q_s = [Q|U] @ [Wq|Wu]^T + (bq+bu+bias)
    gemm2_k<1><<<256, 256, 0, stream>>>(Aq, Bq, cbias, qsb, nullptr, 4096, 1024, KQ, 1024);
    // attention: rowsum pre-pass, then fused V-split QK/sigmoid/align/PV, then ctx reduce
    rowsum_k<<<4096, 256, 0, stream>>>(qsb, vsb, rsum_part);
    fat2_k<<<512, 512, 0, stream>>>(qsb, vsb, vsT, rsum_part, align_out, ctxp);
    ctxred_k<<<2048, 256, 0, stream>>>(ctxp, comb);
    // output = tanh(combined @ fc_w^T + fc_b)
    gemm2_k<2><<<256, 256, 0, stream>>>(comb, Bfc, fcb, out, nullptr, 4096, 1024, 2048, 1024);
}

// Round 11
// 317.834 us; speedup vs baseline: 1.1634x; 1.0264x over previous
//
#include <hip/hip_runtime.h>

// ---------- types ----------
typedef __attribute__((ext_vector_type(8))) short short8;
typedef __attribute__((ext_vector_type(4))) short short4v;
typedef __attribute__((ext_vector_type(4))) float f32x4;

static __device__ __forceinline__ short f2bf(float x) {
    unsigned u = __builtin_bit_cast(unsigned, x);
    unsigned r = (u + 0x7fffu + ((u >> 16) & 1u)) >> 16;
    return (short)r;
}

// async global->LDS, 16B per lane: lds dest = uniform base + lane*16
static __device__ __forceinline__ void gld16(const short* g, short* l) {
    __builtin_amdgcn_global_load_lds((const __attribute__((address_space(1))) void*)g,
                                     (__attribute__((address_space(3))) void*)l, 16, 0, 0);
}

#define QL 512
#define VL 2048
#define DM 1024
#define NH 8
#define DH 128
#define NB 8
#define KQ 1088   // 1024 + 64 (U columns padded)

// ---------- merged prep kernel ----------
// ranges: [0,4) cbias | [4,20) conv | [20,2068) castq | [2068,10260) castv | [10260,26900) buildw
__global__ void prep_k(const float* __restrict__ Q, const float* __restrict__ V,
                       const float* __restrict__ la, const float* __restrict__ cw,
                       const float* __restrict__ cb,
                       const float* __restrict__ Wq, const float* __restrict__ bq,
                       const float* __restrict__ Wv, const float* __restrict__ Wu,
                       const float* __restrict__ bu, const float* __restrict__ bias,
                       const float* __restrict__ fcw,
                       float* __restrict__ cbias, short* __restrict__ Aq,
                       short* __restrict__ comb, short* __restrict__ Vb,
                       short* __restrict__ Bq, short* __restrict__ Bv,
                       short* __restrict__ Bfc) {
    const int blk = blockIdx.x, tid = threadIdx.x;
    if (blk < 4) {
        int i = blk * 256 + tid;
        if (i < DM) cbias[i] = bq[i] + bu[i] + bias[i];
    } else if (blk < 20) {
        int m = (blk - 4) * 256 + tid;
        if (m >= NB * QL) return;
        int b = m >> 9, t = m & 511;
        const float* l = la + b * QL;
        float lm = (t > 0)      ? l[t - 1] : 0.f;
        float l0 = l[t];
        float lp = (t < QL - 1) ? l[t + 1] : 0.f;
        short* row = Aq + (size_t)m * KQ + 1024;
#pragma unroll
        for (int k = 0; k < 10; ++k)
            row[k] = f2bf(cb[k] + lm * cw[k * 3 + 0] + l0 * cw[k * 3 + 1] + lp * cw[k * 3 + 2]);
        for (int k = 10; k < 64; ++k) row[k] = 0;
    } else if (blk < 2068) {
        int id = (blk - 20) * 256 + tid;
        int m = id >> 7, kc = (id & 127) * 8;
        const float* p = Q + (size_t)m * DM + kc;
        float4 f0 = *(const float4*)p;
        float4 f1 = *(const float4*)(p + 4);
        short8 v;
        v[0]=f2bf(f0.x); v[1]=f2bf(f0.y); v[2]=f2bf(f0.z); v[3]=f2bf(f0.w);
        v[4]=f2bf(f1.x); v[5]=f2bf(f1.y); v[6]=f2bf(f1.z); v[7]=f2bf(f1.w);
        *(short8*)(Aq + (size_t)m * KQ + kc) = v;
        *(short8*)(comb + (size_t)m * (2 * DM) + DM + kc) = v;
    } else if (blk < 10260) {
        int id = (blk - 2068) * 256 + tid;
        const float* p = V + (size_t)id * 8;
        float4 f0 = *(const float4*)p;
        float4 f1 = *(const float4*)(p + 4);
        short8 v;
        v[0]=f2bf(f0.x); v[1]=f2bf(f0.y); v[2]=f2bf(f0.z); v[3]=f2bf(f0.w);
        v[4]=f2bf(f1.x); v[5]=f2bf(f1.y); v[6]=f2bf(f1.z); v[7]=f2bf(f1.w);
        *(short8*)(Vb + (size_t)id * 8) = v;
    } else {
        int id = (blk - 10260) * 256 + tid;
        const int nq = DM * KQ;             // 1,114,112
        const int nv = DM * DM;             // 1,048,576
        const int nf = DM * 2 * DM;         // 2,097,152  -> total 16640 blocks
        if (id < nq) {
            int n = id / KQ, k = id % KQ;
            float v = (k < 1024) ? Wq[(size_t)n * 1024 + k]
                                 : ((k < 1034) ? Wu[n * 10 + (k - 1024)] : 0.f);
            Bq[id] = f2bf(v);
        } else if (id < nq + nv) {
            int j = id - nq;
            Bv[j] = f2bf(Wv[j]);
        } else if (id < nq + nv + nf) {
            int j = id - nq - nv;
            Bfc[j] = f2bf(fcw[j]);
        }
    }
}

// ---------- m97-style MFMA GEMM body (4-wave, round-7 measured form) ----------
// MODE 0: v_s — bf16 out + transposed out; MODE 1: q_s — bf16 out; MODE 2: fc — f32 tanh
template <int MODE>
static __device__ __forceinline__ void gemm_body(
    short* As, short* Bs,
    const short* __restrict__ A, const short* __restrict__ B,
    const float* __restrict__ bias, void* __restrict__ out0,
    short* __restrict__ outT, int K, int out_ld, int bm, int bn) {
    const int tid = threadIdx.x;
    const int lane = tid & 63, wave = tid >> 6;
    const int g = lane >> 4, c = lane & 15;
    const int wr = wave >> 1, wc = wave & 1;

    const int srow = lane >> 3, scol = (lane & 7) * 8;
    const short* ag = A + (size_t)(bm * 128 + wave * 32 + srow) * K + scol;
    const short* bg = B + (size_t)(bn * 128 + wave * 32 + srow) * K + scol;

    f32x4 acc[4][4] = {};
    for (int k0 = 0; k0 < K; k0 += 64) {
#pragma unroll
        for (int ch = 0; ch < 4; ++ch) {
            gld16(ag + (size_t)(ch * 8) * K + k0, As + (wave * 32 + ch * 8) * 64);
            gld16(bg + (size_t)(ch * 8) * K + k0, Bs + (wave * 32 + ch * 8) * 64);
        }
        __syncthreads();
#pragma unroll
        for (int ks = 0; ks < 2; ++ks) {
            short8 af[4], bfr[4];
#pragma unroll
            for (int mi = 0; mi < 4; ++mi) af[mi] = *(const short8*)(As + (wr * 64 + mi * 16 + c) * 64 + ks * 32 + g * 8);
#pragma unroll
            for (int ni = 0; ni < 4; ++ni) bfr[ni] = *(const short8*)(Bs + (wc * 64 + ni * 16 + c) * 64 + ks * 32 + g * 8);
#pragma unroll
            for (int mi = 0; mi < 4; ++mi)
#pragma unroll
                for (int ni = 0; ni < 4; ++ni)
                    acc[mi][ni] = __builtin_amdgcn_mfma_f32_16x16x32_bf16(af[mi], bfr[ni], acc[mi][ni], 0, 0, 0);
        }
        __syncthreads();
    }

    const int m0 = bm * 128 + wr * 64, n0 = bn * 128 + wc * 64;
#pragma unroll
    for (int ni = 0; ni < 4; ++ni) {
        int n = n0 + ni * 16 + c;
        float bn_ = bias[n];
#pragma unroll
        for (int mi = 0; mi < 4; ++mi) {
            int mb = m0 + mi * 16 + 4 * g;
            f32x4 v = acc[mi][ni];
            if constexpr (MODE == 2) {
                float* o = (float*)out0;
#pragma unroll
                for (int r = 0; r < 4; ++r)
                    o[(size_t)(mb + r) * out_ld + n] = tanhf(v[r] + bn_);
            } else {
                short* o = (short*)out0;
                short4v pk;
#pragma unroll
                for (int r = 0; r < 4; ++r) {
                    pk[r] = f2bf(v[r] + bn_);
                    o[(size_t)(mb + r) * out_ld + n] = pk[r];
                }
                if constexpr (MODE == 0) {
                    int h = n >> 7, hd = n & 127;
                    int bb = mb >> 11, vv = mb & 2047;
                    *(short4v*)(outT + ((size_t)((bb * NH + h) * DH + hd)) * VL + vv) = pk;
                }
            }
        }
    }
}

// combined v_s (blocks 0..1023) + q_s (blocks 1024..1279) launch
__global__ __launch_bounds__(256) void gemmvq_k(
    const short* __restrict__ Vb, const short* __restrict__ Bvw,
    const float* __restrict__ bv, short* __restrict__ vsb, short* __restrict__ vsT,
    const short* __restrict__ Aq, const short* __restrict__ Bq,
    const float* __restrict__ cbias, short* __restrict__ qsb) {
    __shared__ short As[128 * 64];
    __shared__ short Bs[128 * 64];
    const int blk = blockIdx.x;
    if (blk < 1024) {
        const int x = blk & 7, j = blk >> 3;
        gemm_body<0>(As, Bs, Vb, Bvw, bv, vsb, vsT, 1024, 1024, x * 16 + (j >> 3), j & 7);
    } else {
        const int b2 = blk - 1024;
        const int x = b2 & 7, j = b2 >> 3;
        gemm_body<1>(As, Bs, Aq, Bq, cbias, qsb, nullptr, KQ, 1024, x * 4 + (j >> 3), j & 7);
    }
}

// fc GEMM launch (256 blocks)
__global__ __launch_bounds__(256) void gemmfc_k(
    const short* __restrict__ comb, const short* __restrict__ Bfc,
    const float* __restrict__ fcb, float* __restrict__ out) {
    __shared__ short As[128 * 64];
    __shared__ short Bs[128 * 64];
    const int x = blockIdx.x & 7, j = blockIdx.x >> 3;
    gemm_body<2>(As, Bs, comb, Bfc, fcb, out, nullptr, 2048, 1024, x * 4 + (j >> 3), j & 7);
}

// ---------- rowsum kernel (4-wave, round-7 measured form) ----------
__global__ __launch_bounds__(256) void rowsum_k(
    const short* __restrict__ qs, const short* __restrict__ vs,
    float* __restrict__ rsum_part) {
    __shared__ short As[128 * 64];
    __shared__ short Bs[128 * 64];
    const int blk = blockIdx.x;
    const int xr = blk & 7, t = blk >> 3;
    const int bn = t & 15;
    const int bm = (t >> 4) & 3;
    const int bh = ((t >> 6) << 3) | xr;
    const int h = bh & 7, b = bh >> 3;

    const int tid = threadIdx.x;
    const int lane = tid & 63, wave = tid >> 6;
    const int g = lane >> 4, c = lane & 15;
    const int wr = wave >> 1, wc = wave & 1;
    const float sc = 0.08838834764831845f;   // 1/sqrt(128)

    const int srow = lane >> 3, scol = (lane & 7) * 8;
    const short* ag = qs + (size_t)(b * QL + bm * 128 + wave * 32 + srow) * DM + h * DH + scol;
    const short* bg = vs + (size_t)(b * VL + bn * 128 + wave * 32 + srow) * DM + h * DH + scol;

    f32x4 acc[4][4] = {};
    for (int k0 = 0; k0 < DH; k0 += 64) {
#pragma unroll
        for (int ch = 0; ch < 4; ++ch) {
            gld16(ag + (size_t)(ch * 8) * DM + k0, As + (wave * 32 + ch * 8) * 64);
            gld16(bg + (size_t)(ch * 8) * DM + k0, Bs + (wave * 32 + ch * 8) * 64);
        }
        __syncthreads();
#pragma unroll
        for (int ks = 0; ks < 2; ++ks) {
            short8 af[4], bfr[4];
#pragma unroll
            for (int mi = 0; mi < 4; ++mi) af[mi] = *(const short8*)(As + (wr * 64 + mi * 16 + c) * 64 + ks * 32 + g * 8);
#pragma unroll
            for (int ni = 0; ni < 4; ++ni) bfr[ni] = *(const short8*)(Bs + (wc * 64 + ni * 16 + c) * 64 + ks * 32 + g * 8);
#pragma unroll
            for (int mi = 0; mi < 4; ++mi)
#pragma unroll
                for (int ni = 0; ni < 4; ++ni)
                    acc[mi][ni] = __builtin_amdgcn_mfma_f32_16x16x32_bf16(af[mi], bfr[ni], acc[mi][ni], 0, 0, 0);
        }
        __syncthreads();
    }

    float psum[4][4];
#pragma unroll
    for (int mi = 0; mi < 4; ++mi)
#pragma unroll
        for (int r = 0; r < 4; ++r) psum[mi][r] = 0.f;

    const int m0 = bm * 128 + wr * 64;
#pragma unroll
    for (int ni = 0; ni < 4; ++ni) {
#pragma unroll
        for (int mi = 0; mi < 4; ++mi) {
            f32x4 v = acc[mi][ni];
#pragma unroll
            for (int r = 0; r < 4; ++r)
                psum[mi][r] += __builtin_amdgcn_rcpf(1.f + __expf(-v[r] * sc));
        }
    }
#pragma unroll
    for (int off = 1; off < 16; off <<= 1)
#pragma unroll
        for (int mi = 0; mi < 4; ++mi)
#pragma unroll
            for (int r = 0; r < 4; ++r) psum[mi][r] += __shfl_xor(psum[mi][r], off);
    if (c == 0) {
#pragma unroll
        for (int mi = 0; mi < 4; ++mi)
#pragma unroll
            for (int r = 0; r < 4; ++r) {
                int q = m0 + mi * 16 + 4 * g + r;
                rsum_part[(size_t)(bh * QL + q) * 32 + bn * 2 + wc] = psum[mi][r];
            }
    }
}

// ---------- fused attention kernel, V-split (r7 form + setprio + pad retune + bf16 ctxp) ----------
// Block = (bh, 64-q tile, v-half); 4 waves x 16 q-rows; 16 chunks of 64 v.
__global__ __launch_bounds__(256, 3) void fat2_k(
    const short* __restrict__ qs, const short* __restrict__ vs,
    const short* __restrict__ vsT, const float* __restrict__ rsum_part,
    float* __restrict__ align_out, short* __restrict__ ctxp) {
    __shared__ short Vs[64][132];
    __shared__ short Vt[128][70];
    __shared__ short Pl[4][16][70];
    __shared__ float rsl[64];

    const int blk = blockIdx.x;          // 1024; phys%8 groups bh on one XCD
    const int xr = blk & 7, t = blk >> 3;
    const int vh = t & 1;
    const int qt = (t >> 1) & 7;
    const int bh = ((t >> 4) << 3) | xr;
    const int h = bh & 7, b = bh >> 3;
    const int q0 = qt * 64;
    const int vbeg = vh * 1024;

    const int tid = threadIdx.x, wave = tid >> 6, lane = tid & 63;
    const int g = lane >> 4, c = lane & 15;
    const float sc = 0.08838834764831845f;      // 1/sqrt(128)

    if (tid < 64) {
        const float* p = rsum_part + (size_t)(bh * QL + q0 + tid) * 32;
        float s = 0.f;
#pragma unroll
        for (int jj = 0; jj < 32; ++jj) s += p[jj];
        rsl[tid] = __builtin_amdgcn_rcpf(s);
    }
    __syncthreads();

    float invr[4];
#pragma unroll
    for (int r = 0; r < 4; ++r) invr[r] = rsl[wave * 16 + 4 * g + r];

    // Q fragments (one-time, 16 rows x 128 d per wave)
    short8 qa[4];
    const short* qb = qs + ((size_t)(b * QL + q0 + wave * 16 + c)) * DM + h * DH + g * 8;
#pragma unroll
    for (int ks = 0; ks < 4; ++ks) qa[ks] = *(const short8*)(qb + ks * 32);

    // staging bases
    const int vsrow = tid >> 2, vscq = (tid & 3) * 32;
    const short* vsg = vs + ((size_t)(b * VL + vsrow)) * DM + h * DH + vscq;
    const int vtrow = tid >> 1, vtcq = (tid & 1) * 32;
    const short* vtg = vsT + ((size_t)(bh * DH + vtrow)) * VL + vtcq;

    float* ao = align_out + ((size_t)((h * NB + b) * QL + q0 + wave * 16)) * VL;

    // prologue: load chunk 0 into regs
    short8 pv_s[4], pv_t[4];
#pragma unroll
    for (int i = 0; i < 4; ++i) pv_s[i] = *(const short8*)(vsg + (size_t)vbeg * DM + i * 8);
#pragma unroll
    for (int i = 0; i < 4; ++i) pv_t[i] = *(const short8*)(vtg + vbeg + i * 8);

    f32x4 ctx[8] = {};
    for (int tc = 0; tc < 16; ++tc) {
        const int v0 = vbeg + tc * 64;
        // write staged regs to LDS
#pragma unroll
        for (int i = 0; i < 4; ++i) *(short8*)&Vs[vsrow][vscq + i * 8] = pv_s[i];
#pragma unroll
        for (int i = 0; i < 4; ++i) *(short8*)&Vt[vtrow][vtcq + i * 8] = pv_t[i];
        __syncthreads();
        // T14: issue next chunk's loads early (hide under compute)
        if (tc + 1 < 16) {
            const int v1 = v0 + 64;
#pragma unroll
            for (int i = 0; i < 4; ++i) pv_s[i] = *(const short8*)(vsg + (size_t)v1 * DM + i * 8);
#pragma unroll
            for (int i = 0; i < 4; ++i) pv_t[i] = *(const short8*)(vtg + v1 + i * 8);
        }

        // QK: S chunk 16q x 64v per wave
#pragma unroll
        for (int ni = 0; ni < 4; ++ni) {
            f32x4 s = {0.f, 0.f, 0.f, 0.f};
            __builtin_amdgcn_s_setprio(1);
#pragma unroll
            for (int ks = 0; ks < 4; ++ks)
                s = __builtin_amdgcn_mfma_f32_16x16x32_bf16(qa[ks], *(const short8*)&Vs[ni * 16 + c][ks * 32 + g * 8], s, 0, 0, 0);
            __builtin_amdgcn_s_setprio(0);
#pragma unroll
            for (int r = 0; r < 4; ++r) {
                float pn = __builtin_amdgcn_rcpf(1.f + __expf(-s[r] * sc)) * invr[r];
                __builtin_nontemporal_store(pn, &ao[(size_t)(4 * g + r) * VL + v0 + ni * 16 + c]);
                Pl[wave][4 * g + r][ni * 16 + c] = f2bf(pn);
            }
        }
        // PV: ctx += P_chunk @ Vt_chunk^T
        short8 pa0 = *(const short8*)&Pl[wave][c][g * 8];
        short8 pa1 = *(const short8*)&Pl[wave][c][32 + g * 8];
        __builtin_amdgcn_s_setprio(1);
#pragma unroll
        for (int df = 0; df < 8; ++df) {
            ctx[df] = __builtin_amdgcn_mfma_f32_16x16x32_bf16(pa0, *(const short8*)&Vt[df * 16 + c][g * 8], ctx[df], 0, 0, 0);
            ctx[df] = __builtin_amdgcn_mfma_f32_16x16x32_bf16(pa1, *(const short8*)&Vt[df * 16 + c][32 + g * 8], ctx[df], 0, 0, 0);
        }
        __builtin_amdgcn_s_setprio(0);
        __syncthreads();
    }

    // store partial ctx (bf16) to scratch
    short* cp = ctxp + ((size_t)((bh * 8 + qt) * 2 + vh)) * (64 * 128);
#pragma unroll
    for (int df = 0; df < 8; ++df)
#pragma unroll
        for (int r = 0; r < 4; ++r)
            cp[(size_t)(wave * 16 + 4 * g + r) * 128 + df * 16 + c] = f2bf(ctx[df][r]);
}

// ---------- ctx reduce: comb ctx half = bf16(part0 + part1), bf16 partials ----------
__global__ void ctxred_k(const short* __restrict__ ctxp, short* __restrict__ comb) {
    int id = blockIdx.x * 256 + threadIdx.x;   // 524288 ids, 8 elems each
    int d0 = (id & 15) * 8;
    int r  = (id >> 4) & 63;
    int qt = (id >> 10) & 7;
    int bh = id >> 13;
    int h = bh & 7, b = bh >> 3;
    const short* p0 = ctxp + ((size_t)((bh * 8 + qt) * 2)) * 8192 + r * 128 + d0;
    const short* p1 = p0 + 8192;
    short8 a = *(const short8*)p0;
    short8 bb = *(const short8*)p1;
    short8 o;
#pragma unroll
    for (int jj = 0; jj < 8; ++jj) {
        float fa = __builtin_bit_cast(float, ((unsigned)(unsigned short)a[jj]) << 16);
        float fb = __builtin_bit_cast(float, ((unsigned)(unsigned short)bb[jj]) << 16);
        o[jj] = f2bf(fa + fb);
    }
    *(short8*)(comb + ((size_t)(b * QL + qt * 64 + r)) * (2 * DM) + h * DH + d0) = o;
}

// ---------- launch ----------
extern "C" void kernel_launch(void* const* d_in, const int* in_sizes, int n_in,
                              void* d_out, int out_size, void* d_ws, size_t ws_size,
                              hipStream_t stream) {
    (void)in_sizes; (void)n_in; (void)out_size; (void)ws_size;
    const float* Q    = (const float*)d_in[0];
    const float* V    = (const float*)d_in[1];
    const float* la   = (const float*)d_in[2];
    const float* cw   = (const float*)d_in[3];
    const float* cb   = (const float*)d_in[4];
    const float* Wq   = (const float*)d_in[5];
    const float* bq   = (const float*)d_in[6];
    const float* Wv   = (const float*)d_in[7];
    const float* bv   = (const float*)d_in[8];
    const float* Wu   = (const float*)d_in[9];
    const float* bu   = (const float*)d_in[10];
    const float* bias = (const float*)d_in[11];
    const float* fcw  = (const float*)d_in[12];
    const float* fcb  = (const float*)d_in[13];

    float* out = (float*)d_out;
    float* align_out = out + (size_t)NB * QL * DM;

    char* w = (char*)d_ws;
    short* Vb   = (short*)w; w += (size_t)16384 * 1024 * 2;      // 32 MB
    short* Aq   = (short*)w; w += (size_t)4096 * KQ * 2;         // 8.9 MB
    short* comb = (short*)w; w += (size_t)4096 * 2048 * 2;       // 16 MB
    short* Bq   = (short*)w; w += (size_t)1024 * KQ * 2;         // 2.2 MB
    short* Bvw  = (short*)w; w += (size_t)1024 * 1024 * 2;       // 2 MB
    short* Bfc  = (short*)w; w += (size_t)1024 * 2048 * 2;       // 4 MB
    short* vsb  = (short*)w; w += (size_t)16384 * 1024 * 2;      // 32 MB
    short* vsT  = (short*)w; w += (size_t)16384 * 1024 * 2;      // 32 MB
    short* qsb  = (short*)w; w += (size_t)4096 * 1024 * 2;       // 8 MB
    float* rsum_part = (float*)w; w += (size_t)32768 * 32 * 4;   // 4 MB
    short* ctxp = (short*)w; w += (size_t)1024 * 64 * 128 * 2;   // 16 MB
    float* cbias = (float*)w; w += 1024 * 4;

    // all prep in one launch (ranges: cbias|conv|castq|castv|buildw) — 26900 blocks
    prep_k<<<26900, 256, 0, stream>>>(Q, V, la, cw, cb, Wq, bq, Wv, Wu, bu, bias, fcw,
                                      cbias, Aq, comb, Vb, Bq, Bvw, Bfc);
    // v_s GEMM (1024 blocks) + q_s GEMM (256 blocks) in one launch
    gemmvq_k<<<1280, 256, 0, stream>>>(Vb, Bvw, bv, vsb, vsT, Aq, Bq, cbias, qsb);
    // attention: rowsum pre-pass, then fused V-split QK/sigmoid/align/PV, then ctx reduce
    rowsum_k<<<4096, 256, 0, stream>>>(qsb, vsb, rsum_part);
    fat2_k<<<1024, 256, 0, stream>>>(qsb, vsb, vsT, rsum_part, align_out, ctxp);
    ctxred_k<<<2048, 256, 0, stream>>>(ctxp, comb);
    // output = tanh(combined @ fc_w^T + fc_b)
    gemmfc_k<<<256, 256, 0, stream>>>(comb, Bfc, fcb, out);
}

// Round 12
// 293.561 us; speedup vs baseline: 1.2596x; 1.0827x over previous
//
#include <hip/hip_runtime.h>

// ---------- types ----------
typedef __attribute__((ext_vector_type(8))) short short8;
typedef __attribute__((ext_vector_type(4))) short short4v;
typedef __attribute__((ext_vector_type(4))) float f32x4;

static __device__ __forceinline__ short f2bf(float x) {
    unsigned u = __builtin_bit_cast(unsigned, x);
    unsigned r = (u + 0x7fffu + ((u >> 16) & 1u)) >> 16;
    return (short)r;
}

// async global->LDS, 16B per lane: lds dest = uniform base + lane*16
static __device__ __forceinline__ void gld16(const short* g, short* l) {
    __builtin_amdgcn_global_load_lds((const __attribute__((address_space(1))) void*)g,
                                     (__attribute__((address_space(3))) void*)l, 16, 0, 0);
}

#define QL 512
#define VL 2048
#define DM 1024
#define NH 8
#define DH 128
#define NB 8
#define KQ 1088   // 1024 + 64 (U columns padded)

// -sc*log2(e): sigmoid(s*sc) = rcp(1 + exp2(s*KSIG))
#define KSIG (-0.12751542401539644f)

// ---------- merged prep kernel ----------
// ranges: [0,4) cbias | [4,20) conv | [20,2068) castq | [2068,10260) castv | [10260,26900) buildw
__global__ void prep_k(const float* __restrict__ Q, const float* __restrict__ V,
                       const float* __restrict__ la, const float* __restrict__ cw,
                       const float* __restrict__ cb,
                       const float* __restrict__ Wq, const float* __restrict__ bq,
                       const float* __restrict__ Wv, const float* __restrict__ Wu,
                       const float* __restrict__ bu, const float* __restrict__ bias,
                       const float* __restrict__ fcw,
                       float* __restrict__ cbias, short* __restrict__ Aq,
                       short* __restrict__ comb, short* __restrict__ Vb,
                       short* __restrict__ Bq, short* __restrict__ Bv,
                       short* __restrict__ Bfc) {
    const int blk = blockIdx.x, tid = threadIdx.x;
    if (blk < 4) {
        int i = blk * 256 + tid;
        if (i < DM) cbias[i] = bq[i] + bu[i] + bias[i];
    } else if (blk < 20) {
        int m = (blk - 4) * 256 + tid;
        if (m >= NB * QL) return;
        int b = m >> 9, t = m & 511;
        const float* l = la + b * QL;
        float lm = (t > 0)      ? l[t - 1] : 0.f;
        float l0 = l[t];
        float lp = (t < QL - 1) ? l[t + 1] : 0.f;
        short* row = Aq + (size_t)m * KQ + 1024;
#pragma unroll
        for (int k = 0; k < 10; ++k)
            row[k] = f2bf(cb[k] + lm * cw[k * 3 + 0] + l0 * cw[k * 3 + 1] + lp * cw[k * 3 + 2]);
        for (int k = 10; k < 64; ++k) row[k] = 0;
    } else if (blk < 2068) {
        int id = (blk - 20) * 256 + tid;
        int m = id >> 7, kc = (id & 127) * 8;
        const float* p = Q + (size_t)m * DM + kc;
        float4 f0 = *(const float4*)p;
        float4 f1 = *(const float4*)(p + 4);
        short8 v;
        v[0]=f2bf(f0.x); v[1]=f2bf(f0.y); v[2]=f2bf(f0.z); v[3]=f2bf(f0.w);
        v[4]=f2bf(f1.x); v[5]=f2bf(f1.y); v[6]=f2bf(f1.z); v[7]=f2bf(f1.w);
        *(short8*)(Aq + (size_t)m * KQ + kc) = v;
        *(short8*)(comb + (size_t)m * (2 * DM) + DM + kc) = v;
    } else if (blk < 10260) {
        int id = (blk - 2068) * 256 + tid;
        const float* p = V + (size_t)id * 8;
        float4 f0 = *(const float4*)p;
        float4 f1 = *(const float4*)(p + 4);
        short8 v;
        v[0]=f2bf(f0.x); v[1]=f2bf(f0.y); v[2]=f2bf(f0.z); v[3]=f2bf(f0.w);
        v[4]=f2bf(f1.x); v[5]=f2bf(f1.y); v[6]=f2bf(f1.z); v[7]=f2bf(f1.w);
        *(short8*)(Vb + (size_t)id * 8) = v;
    } else {
        int id = (blk - 10260) * 256 + tid;
        const int nq = DM * KQ;             // 1,114,112
        const int nv = DM * DM;             // 1,048,576
        const int nf = DM * 2 * DM;         // 2,097,152  -> total 16640 blocks
        if (id < nq) {
            int n = id / KQ, k = id % KQ;
            float v = (k < 1024) ? Wq[(size_t)n * 1024 + k]
                                 : ((k < 1034) ? Wu[n * 10 + (k - 1024)] : 0.f);
            Bq[id] = f2bf(v);
        } else if (id < nq + nv) {
            int j = id - nq;
            Bv[j] = f2bf(Wv[j]);
        } else if (id < nq + nv + nf) {
            int j = id - nq - nv;
            Bfc[j] = f2bf(fcw[j]);
        }
    }
}

// ---------- m97-style MFMA GEMM body (4-wave, round-7 measured form) ----------
// MODE 0: v_s — bf16 out + transposed out; MODE 1: q_s — bf16 out; MODE 2: fc — f32 tanh
template <int MODE>
static __device__ __forceinline__ void gemm_body(
    short* As, short* Bs,
    const short* __restrict__ A, const short* __restrict__ B,
    const float* __restrict__ bias, void* __restrict__ out0,
    short* __restrict__ outT, int K, int out_ld, int bm, int bn) {
    const int tid = threadIdx.x;
    const int lane = tid & 63, wave = tid >> 6;
    const int g = lane >> 4, c = lane & 15;
    const int wr = wave >> 1, wc = wave & 1;

    const int srow = lane >> 3, scol = (lane & 7) * 8;
    const short* ag = A + (size_t)(bm * 128 + wave * 32 + srow) * K + scol;
    const short* bg = B + (size_t)(bn * 128 + wave * 32 + srow) * K + scol;

    f32x4 acc[4][4] = {};
    for (int k0 = 0; k0 < K; k0 += 64) {
#pragma unroll
        for (int ch = 0; ch < 4; ++ch) {
            gld16(ag + (size_t)(ch * 8) * K + k0, As + (wave * 32 + ch * 8) * 64);
            gld16(bg + (size_t)(ch * 8) * K + k0, Bs + (wave * 32 + ch * 8) * 64);
        }
        __syncthreads();
#pragma unroll
        for (int ks = 0; ks < 2; ++ks) {
            short8 af[4], bfr[4];
#pragma unroll
            for (int mi = 0; mi < 4; ++mi) af[mi] = *(const short8*)(As + (wr * 64 + mi * 16 + c) * 64 + ks * 32 + g * 8);
#pragma unroll
            for (int ni = 0; ni < 4; ++ni) bfr[ni] = *(const short8*)(Bs + (wc * 64 + ni * 16 + c) * 64 + ks * 32 + g * 8);
#pragma unroll
            for (int mi = 0; mi < 4; ++mi)
#pragma unroll
                for (int ni = 0; ni < 4; ++ni)
                    acc[mi][ni] = __builtin_amdgcn_mfma_f32_16x16x32_bf16(af[mi], bfr[ni], acc[mi][ni], 0, 0, 0);
        }
        __syncthreads();
    }

    const int m0 = bm * 128 + wr * 64, n0 = bn * 128 + wc * 64;
#pragma unroll
    for (int ni = 0; ni < 4; ++ni) {
        int n = n0 + ni * 16 + c;
        float bn_ = bias[n];
#pragma unroll
        for (int mi = 0; mi < 4; ++mi) {
            int mb = m0 + mi * 16 + 4 * g;
            f32x4 v = acc[mi][ni];
            if constexpr (MODE == 2) {
                float* o = (float*)out0;
#pragma unroll
                for (int r = 0; r < 4; ++r)
                    o[(size_t)(mb + r) * out_ld + n] = tanhf(v[r] + bn_);
            } else {
                short* o = (short*)out0;
                short4v pk;
#pragma unroll
                for (int r = 0; r < 4; ++r) {
                    pk[r] = f2bf(v[r] + bn_);
                    o[(size_t)(mb + r) * out_ld + n] = pk[r];
                }
                if constexpr (MODE == 0) {
                    int h = n >> 7, hd = n & 127;
                    int bb = mb >> 11, vv = mb & 2047;
                    *(short4v*)(outT + ((size_t)((bb * NH + h) * DH + hd)) * VL + vv) = pk;
                }
            }
        }
    }
}

// combined v_s (blocks 0..1023) + q_s (blocks 1024..1279) launch
__global__ __launch_bounds__(256) void gemmvq_k(
    const short* __restrict__ Vb, const short* __restrict__ Bvw,
    const float* __restrict__ bv, short* __restrict__ vsb, short* __restrict__ vsT,
    const short* __restrict__ Aq, const short* __restrict__ Bq,
    const float* __restrict__ cbias, short* __restrict__ qsb) {
    __shared__ short As[128 * 64];
    __shared__ short Bs[128 * 64];
    const int blk = blockIdx.x;
    if (blk < 1024) {
        const int x = blk & 7, j = blk >> 3;
        gemm_body<0>(As, Bs, Vb, Bvw, bv, vsb, vsT, 1024, 1024, x * 16 + (j >> 3), j & 7);
    } else {
        const int b2 = blk - 1024;
        const int x = b2 & 7, j = b2 >> 3;
        gemm_body<1>(As, Bs, Aq, Bq, cbias, qsb, nullptr, KQ, 1024, x * 4 + (j >> 3), j & 7);
    }
}

// fc GEMM launch (256 blocks)
__global__ __launch_bounds__(256) void gemmfc_k(
    const short* __restrict__ comb, const short* __restrict__ Bfc,
    const float* __restrict__ fcb, float* __restrict__ out) {
    __shared__ short As[128 * 64];
    __shared__ short Bs[128 * 64];
    const int x = blockIdx.x & 7, j = blockIdx.x >> 3;
    gemm_body<2>(As, Bs, comb, Bfc, fcb, out, nullptr, 2048, 1024, x * 4 + (j >> 3), j & 7);
}

// ---------- rowsum kernel (4-wave, round-7 measured form) ----------
__global__ __launch_bounds__(256) void rowsum_k(
    const short* __restrict__ qs, const short* __restrict__ vs,
    float* __restrict__ rsum_part) {
    __shared__ short As[128 * 64];
    __shared__ short Bs[128 * 64];
    const int blk = blockIdx.x;
    const int xr = blk & 7, t = blk >> 3;
    const int bn = t & 15;
    const int bm = (t >> 4) & 3;
    const int bh = ((t >> 6) << 3) | xr;
    const int h = bh & 7, b = bh >> 3;

    const int tid = threadIdx.x;
    const int lane = tid & 63, wave = tid >> 6;
    const int g = lane >> 4, c = lane & 15;
    const int wr = wave >> 1, wc = wave & 1;

    const int srow = lane >> 3, scol = (lane & 7) * 8;
    const short* ag = qs + (size_t)(b * QL + bm * 128 + wave * 32 + srow) * DM + h * DH + scol;
    const short* bg = vs + (size_t)(b * VL + bn * 128 + wave * 32 + srow) * DM + h * DH + scol;

    f32x4 acc[4][4] = {};
    for (int k0 = 0; k0 < DH; k0 += 64) {
#pragma unroll
        for (int ch = 0; ch < 4; ++ch) {
            gld16(ag + (size_t)(ch * 8) * DM + k0, As + (wave * 32 + ch * 8) * 64);
            gld16(bg + (size_t)(ch * 8) * DM + k0, Bs + (wave * 32 + ch * 8) * 64);
        }
        __syncthreads();
#pragma unroll
        for (int ks = 0; ks < 2; ++ks) {
            short8 af[4], bfr[4];
#pragma unroll
            for (int mi = 0; mi < 4; ++mi) af[mi] = *(const short8*)(As + (wr * 64 + mi * 16 + c) * 64 + ks * 32 + g * 8);
#pragma unroll
            for (int ni = 0; ni < 4; ++ni) bfr[ni] = *(const short8*)(Bs + (wc * 64 + ni * 16 + c) * 64 + ks * 32 + g * 8);
#pragma unroll
            for (int mi = 0; mi < 4; ++mi)
#pragma unroll
                for (int ni = 0; ni < 4; ++ni)
                    acc[mi][ni] = __builtin_amdgcn_mfma_f32_16x16x32_bf16(af[mi], bfr[ni], acc[mi][ni], 0, 0, 0);
        }
        __syncthreads();
    }

    float psum[4][4];
#pragma unroll
    for (int mi = 0; mi < 4; ++mi)
#pragma unroll
        for (int r = 0; r < 4; ++r) psum[mi][r] = 0.f;

    const int m0 = bm * 128 + wr * 64;
#pragma unroll
    for (int ni = 0; ni < 4; ++ni) {
#pragma unroll
        for (int mi = 0; mi < 4; ++mi) {
            f32x4 v = acc[mi][ni];
#pragma unroll
            for (int r = 0; r < 4; ++r)
                psum[mi][r] += __builtin_amdgcn_rcpf(1.f + __builtin_amdgcn_exp2f(v[r] * KSIG));
        }
    }
#pragma unroll
    for (int off = 1; off < 16; off <<= 1)
#pragma unroll
        for (int mi = 0; mi < 4; ++mi)
#pragma unroll
            for (int r = 0; r < 4; ++r) psum[mi][r] += __shfl_xor(psum[mi][r], off);
    if (c == 0) {
#pragma unroll
        for (int mi = 0; mi < 4; ++mi)
#pragma unroll
            for (int r = 0; r < 4; ++r) {
                int q = m0 + mi * 16 + 4 * g + r;
                rsum_part[(size_t)(bh * QL + q) * 32 + bn * 2 + wc] = psum[mi][r];
            }
    }
}

// ---------- fused attention kernel, V-split (exact r7 form; bf16 ctxp) ----------
// Block = (bh, 64-q tile, v-half); 4 waves x 16 q-rows; 16 chunks of 64 v.
__global__ __launch_bounds__(256, 3) void fat2_k(
    const short* __restrict__ qs, const short* __restrict__ vs,
    const short* __restrict__ vsT, const float* __restrict__ rsum_part,
    float* __restrict__ align_out, short* __restrict__ ctxp) {
    __shared__ short Vs[64][136];
    __shared__ short Vt[128][72];
    __shared__ short Pl[4][16][72];
    __shared__ float rsl[64];

    const int blk = blockIdx.x;          // 1024; phys%8 groups bh on one XCD
    const int xr = blk & 7, t = blk >> 3;
    const int vh = t & 1;
    const int qt = (t >> 1) & 7;
    const int bh = ((t >> 4) << 3) | xr;
    const int h = bh & 7, b = bh >> 3;
    const int q0 = qt * 64;
    const int vbeg = vh * 1024;

    const int tid = threadIdx.x, wave = tid >> 6, lane = tid & 63;
    const int g = lane >> 4, c = lane & 15;

    if (tid < 64) {
        const float* p = rsum_part + (size_t)(bh * QL + q0 + tid) * 32;
        float s = 0.f;
#pragma unroll
        for (int jj = 0; jj < 32; ++jj) s += p[jj];
        rsl[tid] = __builtin_amdgcn_rcpf(s);
    }
    __syncthreads();

    float invr[4];
#pragma unroll
    for (int r = 0; r < 4; ++r) invr[r] = rsl[wave * 16 + 4 * g + r];

    // Q fragments (one-time, 16 rows x 128 d per wave)
    short8 qa[4];
    const short* qb = qs + ((size_t)(b * QL + q0 + wave * 16 + c)) * DM + h * DH + g * 8;
#pragma unroll
    for (int ks = 0; ks < 4; ++ks) qa[ks] = *(const short8*)(qb + ks * 32);

    // staging bases
    const int vsrow = tid >> 2, vscq = (tid & 3) * 32;
    const short* vsg = vs + ((size_t)(b * VL + vsrow)) * DM + h * DH + vscq;
    const int vtrow = tid >> 1, vtcq = (tid & 1) * 32;
    const short* vtg = vsT + ((size_t)(bh * DH + vtrow)) * VL + vtcq;

    float* ao = align_out + ((size_t)((h * NB + b) * QL + q0 + wave * 16)) * VL;

    // prologue: load chunk 0 into regs
    short8 pv_s[4], pv_t[4];
#pragma unroll
    for (int i = 0; i < 4; ++i) pv_s[i] = *(const short8*)(vsg + (size_t)vbeg * DM + i * 8);
#pragma unroll
    for (int i = 0; i < 4; ++i) pv_t[i] = *(const short8*)(vtg + vbeg + i * 8);

    f32x4 ctx[8] = {};
    for (int tc = 0; tc < 16; ++tc) {
        const int v0 = vbeg + tc * 64;
        // write staged regs to LDS
#pragma unroll
        for (int i = 0; i < 4; ++i) *(short8*)&Vs[vsrow][vscq + i * 8] = pv_s[i];
#pragma unroll
        for (int i = 0; i < 4; ++i) *(short8*)&Vt[vtrow][vtcq + i * 8] = pv_t[i];
        __syncthreads();
        // T14: issue next chunk's loads early (hide under compute)
        if (tc + 1 < 16) {
            const int v1 = v0 + 64;
#pragma unroll
            for (int i = 0; i < 4; ++i) pv_s[i] = *(const short8*)(vsg + (size_t)v1 * DM + i * 8);
#pragma unroll
            for (int i = 0; i < 4; ++i) pv_t[i] = *(const short8*)(vtg + v1 + i * 8);
        }

        // QK: S chunk 16q x 64v per wave
#pragma unroll
        for (int ni = 0; ni < 4; ++ni) {
            f32x4 s = {0.f, 0.f, 0.f, 0.f};
#pragma unroll
            for (int ks = 0; ks < 4; ++ks)
                s = __builtin_amdgcn_mfma_f32_16x16x32_bf16(qa[ks], *(const short8*)&Vs[ni * 16 + c][ks * 32 + g * 8], s, 0, 0, 0);
#pragma unroll
            for (int r = 0; r < 4; ++r) {
                float pn = __builtin_amdgcn_rcpf(1.f + __builtin_amdgcn_exp2f(s[r] * KSIG)) * invr[r];
                __builtin_nontemporal_store(pn, &ao[(size_t)(4 * g + r) * VL + v0 + ni * 16 + c]);
                Pl[wave][4 * g + r][ni * 16 + c] = f2bf(pn);
            }
        }
        // PV: ctx += P_chunk @ Vt_chunk^T
        short8 pa0 = *(const short8*)&Pl[wave][c][g * 8];
        short8 pa1 = *(const short8*)&Pl[wave][c][32 + g * 8];
#pragma unroll
        for (int df = 0; df < 8; ++df) {
            ctx[df] = __builtin_amdgcn_mfma_f32_16x16x32_bf16(pa0, *(const short8*)&Vt[df * 16 + c][g * 8], ctx[df], 0, 0, 0);
            ctx[df] = __builtin_amdgcn_mfma_f32_16x16x32_bf16(pa1, *(const short8*)&Vt[df * 16 + c][32 + g * 8], ctx[df], 0, 0, 0);
        }
        __syncthreads();
    }

    // store partial ctx (bf16) to scratch
    short* cp = ctxp + ((size_t)((bh * 8 + qt) * 2 + vh)) * (64 * 128);
#pragma unroll
    for (int df = 0; df < 8; ++df)
#pragma unroll
        for (int r = 0; r < 4; ++r)
            cp[(size_t)(wave * 16 + 4 * g + r) * 128 + df * 16 + c] = f2bf(ctx[df][r]);
}

// ---------- ctx reduce: comb ctx half = bf16(part0 + part1), bf16 partials ----------
__global__ void ctxred_k(const short* __restrict__ ctxp, short* __restrict__ comb) {
    int id = blockIdx.x * 256 + threadIdx.x;   // 524288 ids, 8 elems each
    int d0 = (id & 15) * 8;
    int r  = (id >> 4) & 63;
    int qt = (id >> 10) & 7;
    int bh = id >> 13;
    int h = bh & 7, b = bh >> 3;
    const short* p0 = ctxp + ((size_t)((bh * 8 + qt) * 2)) * 8192 + r * 128 + d0;
    const short* p1 = p0 + 8192;
    short8 a = *(const short8*)p0;
    short8 bb = *(const short8*)p1;
    short8 o;
#pragma unroll
    for (int jj = 0; jj < 8; ++jj) {
        float fa = __builtin_bit_cast(float, ((unsigned)(unsigned short)a[jj]) << 16);
        float fb = __builtin_bit_cast(float, ((unsigned)(unsigned short)bb[jj]) << 16);
        o[jj] = f2bf(fa + fb);
    }
    *(short8*)(comb + ((size_t)(b * QL + qt * 64 + r)) * (2 * DM) + h * DH + d0) = o;
}

// ---------- launch ----------
extern "C" void kernel_launch(void* const* d_in, const int* in_sizes, int n_in,
                              void* d_out, int out_size, void* d_ws, size_t ws_size,
                              hipStream_t stream) {
    (void)in_sizes; (void)n_in; (void)out_size; (void)ws_size;
    const float* Q    = (const float*)d_in[0];
    const float* V    = (const float*)d_in[1];
    const float* la   = (const float*)d_in[2];
    const float* cw   = (const float*)d_in[3];
    const float* cb   = (const float*)d_in[4];
    const float* Wq   = (const float*)d_in[5];
    const float* bq   = (const float*)d_in[6];
    const float* Wv   = (const float*)d_in[7];
    const float* bv   = (const float*)d_in[8];
    const float* Wu   = (const float*)d_in[9];
    const float* bu   = (const float*)d_in[10];
    const float* bias = (const float*)d_in[11];
    const float* fcw  = (const float*)d_in[12];
    const float* fcb  = (const float*)d_in[13];

    float* out = (float*)d_out;
    float* align_out = out + (size_t)NB * QL * DM;

    char* w = (char*)d_ws;
    short* Vb   = (short*)w; w += (size_t)16384 * 1024 * 2;      // 32 MB
    short* Aq   = (short*)w; w += (size_t)4096 * KQ * 2;         // 8.9 MB
    short* comb = (short*)w; w += (size_t)4096 * 2048 * 2;       // 16 MB
    short* Bq   = (short*)w; w += (size_t)1024 * KQ * 2;         // 2.2 MB
    short* Bvw  = (short*)w; w += (size_t)1024 * 1024 * 2;       // 2 MB
    short* Bfc  = (short*)w; w += (size_t)1024 * 2048 * 2;       // 4 MB
    short* vsb  = (short*)w; w += (size_t)16384 * 1024 * 2;      // 32 MB
    short* vsT  = (short*)w; w += (size_t)16384 * 1024 * 2;      // 32 MB
    short* qsb  = (short*)w; w += (size_t)4096 * 1024 * 2;       // 8 MB
    float* rsum_part = (float*)w; w += (size_t)32768 * 32 * 4;   // 4 MB
    short* ctxp = (short*)w; w += (size_t)1024 * 64 * 128 * 2;   // 16 MB
    float* cbias = (float*)w; w += 1024 * 4;

    // all prep in one launch (ranges: cbias|conv|castq|castv|buildw) — 26900 blocks
    prep_k<<<26900, 256, 0, stream>>>(Q, V, la, cw, cb, Wq, bq, Wv, Wu, bu, bias, fcw,
                                      cbias, Aq, comb, Vb, Bq, Bvw, Bfc);
    // v_s GEMM (1024 blocks) + q_s GEMM (256 blocks) in one launch
    gemmvq_k<<<1280, 256, 0, stream>>>(Vb, Bvw, bv, vsb, vsT, Aq, Bq, cbias, qsb);
    // attention: rowsum pre-pass, then fused V-split QK/sigmoid/align/PV, then ctx reduce
    rowsum_k<<<4096, 256, 0, stream>>>(qsb, vsb, rsum_part);
    fat2_k<<<1024, 256, 0, stream>>>(qsb, vsb, vsT, rsum_part, align_out, ctxp);
    ctxred_k<<<2048, 256, 0, stream>>>(ctxp, comb);
    // output = tanh(combined @ fc_w^T + fc_b)
    gemmfc_k<<<256, 256, 0, stream>>>(comb, Bfc, fcb, out);
}